// Round 4
// baseline (351.978 us; speedup 1.0000x reference)
//
#include <hip/hip_runtime.h>
#include <math.h>

#define B_ 4
#define S_ 2048
#define E_ 1024
#define H_ 16
#define D_ 64
#define MRD 32

typedef __bf16 bf16x8 __attribute__((ext_vector_type(8)));
typedef float f32x4 __attribute__((ext_vector_type(4)));
typedef unsigned short us8 __attribute__((ext_vector_type(8)));
typedef unsigned short us4 __attribute__((ext_vector_type(4)));

union frag_cvt { us8 u; bf16x8 b; };
union h_cvt { __bf16 h; unsigned short u; };

__device__ __forceinline__ unsigned short bhi(float x) {
    h_cvt c; c.h = (__bf16)x; return c.u;
}
__device__ __forceinline__ float bf16_f(unsigned short h) {
    union { unsigned int u; float f; } c;
    c.u = ((unsigned int)h) << 16;
    return c.f;
}

__device__ __forceinline__ void async_copy16(const void* g, void* l) {
    __builtin_amdgcn_global_load_lds(
        (const __attribute__((address_space(1))) void*)g,
        (__attribute__((address_space(3))) void*)l,
        16, 0, 0);
}

__device__ __forceinline__ f32x4 mf16(const frag_cvt& a, const frag_cvt& b, f32x4 c) {
    return __builtin_amdgcn_mfma_f32_16x16x32_bf16(a.b, b.b, c, 0, 0, 0);
}

#define QSCL 0.18033688f    // 0.125 * log2(e) — folded into Qb at projection
#define L2E  1.44269504f

// ---------------------------------------------------------------------------
// Convert pass: in[R][K] fp32 -> out[R][K] bf16, PLAIN row-major.
// ---------------------------------------------------------------------------
__global__ __launch_bounds__(128) void cvt_bf16(
    const float* __restrict__ in, unsigned short* __restrict__ out, int K)
{
    const int r  = blockIdx.x;
    const int k8 = threadIdx.x * 8;
    if (k8 >= K) return;
    const float* p = in + (size_t)r * K + k8;
    float4 a = *(const float4*)p;
    float4 b = *(const float4*)(p + 4);
    float xs[8] = {a.x, a.y, a.z, a.w, b.x, b.y, b.z, b.w};
    us8 hu;
#pragma unroll
    for (int j = 0; j < 8; ++j) hu[j] = bhi(xs[j]);
    *(us8*)&out[(size_t)r * K + k8] = hu;
}

// ---------------------------------------------------------------------------
// Split pass: in[R][K] fp32 -> out[R][2K] bf16 {hi | lo}, PLAIN.
// ---------------------------------------------------------------------------
__global__ __launch_bounds__(128) void split_hilo(
    const float* __restrict__ in, unsigned short* __restrict__ out, int K)
{
    const int r  = blockIdx.x;
    const int k8 = threadIdx.x * 8;
    if (k8 >= K) return;
    const float* p = in + (size_t)r * K + k8;
    float4 a = *(const float4*)p;
    float4 b = *(const float4*)(p + 4);
    float xs[8] = {a.x, a.y, a.z, a.w, b.x, b.y, b.z, b.w};
    us8 hu, lu;
#pragma unroll
    for (int j = 0; j < 8; ++j) {
        unsigned short hb = bhi(xs[j]);
        hu[j] = hb;
        lu[j] = bhi(xs[j] - bf16_f(hb));
    }
    *(us8*)&out[(size_t)r * 2 * K + k8]     = hu;
    *(us8*)&out[(size_t)r * 2 * K + K + k8] = lu;
}

// ---------------------------------------------------------------------------
// Stage one 128x64-bf16 unit (16 KB) into LDS via global_load_lds width 16.
// Global source is pre-swizzled (granule XOR with row&7) so that the linear
// LDS destination holds the swizzled layout the frag reads expect.
// 512 threads, 2 loads each.
// ---------------------------------------------------------------------------
__device__ __forceinline__ void stage_unit(const unsigned short* g, int grs,
                                           unsigned short* lu, int t)
{
#pragma unroll
    for (int l = 0; l < 2; ++l) {
        const int f  = l * 512 + t;
        const int ri = f >> 3;                         // row in unit (0..127)
        const int cs = ((f & 7) ^ (ri & 7)) * 8;       // swizzled src col (elems)
        async_copy16(g + (size_t)ri * grs + cs,
                     lu + l * 4096 + (t >> 6) * 512);  // wave-uniform LDS base
    }
}

// ---------------------------------------------------------------------------
// m201-geometry bf16 NT GEMM: BM=BN=256, BK=64, 512 thr = 8 waves (2M x 4N),
// wave tile 128x64, acc 8x4 f32x4.  LDS 2 x 64 KB (A 256x64 @0, B 256x64
// @32768B), 4 units of 128x64 per buffer half.
// Per K-tile, 4 phases:
//   P1: read af0(8xb128)+bf0(4); stage A0,A1(k+1); bar; 16 MFMA; bar
//   P2: read af1(8);             stage B0,B1(k+1); bar; 16 MFMA; bar
//   P3: read bf1(4);                               bar; 16 MFMA; bar
//   P4:                                                 16 MFMA
//   boundary: vmcnt(0) (all k+1 loads issued >=2 phases ago) ; bar
//
// MODE 0: QKV projection, K=1024. Region epilogue -> Qb / K2 / Vt2.
// MODE 1: out projection, 3-term split via virtual K=3072 concat
//         A=[ah|ah|al] (stored [M][2048]={hi|lo}), B=[bh|bl|bh]
//         (stored [N][2048]={hi|lo}); pure source-offset remap.
// ---------------------------------------------------------------------------
template<int MODE>
__global__ __launch_bounds__(512, 2) void gemm256(
    const unsigned short* __restrict__ Ag, const unsigned short* __restrict__ Bg,
    const float* __restrict__ bias,
    unsigned short* __restrict__ O0, unsigned short* __restrict__ O1,
    unsigned short* __restrict__ O2, float* __restrict__ Cf)
{
    constexpr int KD = (MODE == 0) ? 1024 : 3072;  // logical K
    constexpr int NT = KD / 64;
    constexpr int AS = (MODE == 0) ? 1024 : 2048;  // A row stride (elems)
    constexpr int BS = (MODE == 0) ? 1024 : 2048;  // B row stride

    __shared__ unsigned short sbuf[2][32768];      // per buf: A@0, B@16384 (us)

    const int t    = threadIdx.x;
    const int lane = t & 63;
    const int w    = t >> 6;
    const int ln   = lane & 15;
    const int quad = lane >> 4;
    const int wr   = w >> 2;       // 0..1  (M half)
    const int wc   = w & 3;        // 0..3  (N quarter)
    const int m0   = blockIdx.x * 256;
    const int n0   = blockIdx.y * 256;

    // logical K-offset -> source column in the stored [hi|lo] layout
    auto mapA = [](int kk) -> int {
        return (MODE == 0) ? kk : (kk < 1024 ? kk : kk - 1024);
    };
    auto mapB = [](int kk) -> int {
        return (MODE == 0) ? kk : (kk < 2048 ? kk : kk - 2048);
    };

    const int swz = (ln & 7) << 3;            // read-side granule swizzle
    const int kq0 = (quad * 8) ^ swz;         // ks=0 frag offset within row
    const int kq1 = (32 + quad * 8) ^ swz;    // ks=1

    // LDS row bases (ushort offsets)
    const int aBase = wr * 8192;                                  // A unit (wr)
    const int bBase = 16384 + (wc >> 1) * 8192 + (wc & 1) * 64 * 64;

    f32x4 acc[8][4];
#pragma unroll
    for (int i = 0; i < 8; ++i)
#pragma unroll
        for (int j = 0; j < 4; ++j)
            acc[i][j] = (f32x4){0.f, 0.f, 0.f, 0.f};

    // ---- prologue: stage tile 0 (4 units, 8 loads/thread) -----------------
    stage_unit(Ag + (size_t)m0 * AS + mapA(0),          AS, &sbuf[0][0],     t);
    stage_unit(Ag + (size_t)(m0 + 128) * AS + mapA(0),  AS, &sbuf[0][8192],  t);
    stage_unit(Bg + (size_t)n0 * BS + mapB(0),          BS, &sbuf[0][16384], t);
    stage_unit(Bg + (size_t)(n0 + 128) * BS + mapB(0),  BS, &sbuf[0][24576], t);
    asm volatile("s_waitcnt vmcnt(0)" ::: "memory");
    __builtin_amdgcn_s_barrier();

    for (int k = 0; k < NT; ++k) {
        unsigned short* bufc = sbuf[k & 1];
        unsigned short* bufn = sbuf[(k & 1) ^ 1];
        const bool pf = (k + 1 < NT);
        const int kk1 = (k + 1) * 64;
        frag_cvt af0[4][2], af1[4][2], bf0[2][2], bf1[2][2];

        // ========== P1: read af0 + bf0; stage A-units(k+1) ================
#pragma unroll
        for (int ii = 0; ii < 4; ++ii) {
            const int ra = aBase + (ii * 16 + ln) * 64;
            af0[ii][0].u = *(const us8*)&bufc[ra + kq0];
            af0[ii][1].u = *(const us8*)&bufc[ra + kq1];
        }
#pragma unroll
        for (int j = 0; j < 2; ++j) {
            const int rb = bBase + (j * 16 + ln) * 64;
            bf0[j][0].u = *(const us8*)&bufc[rb + kq0];
            bf0[j][1].u = *(const us8*)&bufc[rb + kq1];
        }
        if (pf) {
            stage_unit(Ag + (size_t)m0 * AS + mapA(kk1),         AS, &bufn[0],    t);
            stage_unit(Ag + (size_t)(m0 + 128) * AS + mapA(kk1), AS, &bufn[8192], t);
        }
        __builtin_amdgcn_s_barrier();
        __builtin_amdgcn_s_setprio(1);
#pragma unroll
        for (int ii = 0; ii < 4; ++ii)
#pragma unroll
            for (int j = 0; j < 2; ++j) {
                acc[ii][j] = mf16(af0[ii][0], bf0[j][0], acc[ii][j]);
                acc[ii][j] = mf16(af0[ii][1], bf0[j][1], acc[ii][j]);
            }
        __builtin_amdgcn_s_setprio(0);
        __builtin_amdgcn_s_barrier();

        // ========== P2: read af1; stage B-units(k+1) ======================
#pragma unroll
        for (int ii = 0; ii < 4; ++ii) {
            const int ra = aBase + ((ii + 4) * 16 + ln) * 64;
            af1[ii][0].u = *(const us8*)&bufc[ra + kq0];
            af1[ii][1].u = *(const us8*)&bufc[ra + kq1];
        }
        if (pf) {
            stage_unit(Bg + (size_t)n0 * BS + mapB(kk1),         BS, &bufn[16384], t);
            stage_unit(Bg + (size_t)(n0 + 128) * BS + mapB(kk1), BS, &bufn[24576], t);
        }
        __builtin_amdgcn_s_barrier();
        __builtin_amdgcn_s_setprio(1);
#pragma unroll
        for (int ii = 0; ii < 4; ++ii)
#pragma unroll
            for (int j = 0; j < 2; ++j) {
                acc[ii + 4][j] = mf16(af1[ii][0], bf0[j][0], acc[ii + 4][j]);
                acc[ii + 4][j] = mf16(af1[ii][1], bf0[j][1], acc[ii + 4][j]);
            }
        __builtin_amdgcn_s_setprio(0);
        __builtin_amdgcn_s_barrier();

        // ========== P3: read bf1; MFMA (af1 x bf1) ========================
#pragma unroll
        for (int j = 0; j < 2; ++j) {
            const int rb = bBase + ((j + 2) * 16 + ln) * 64;
            bf1[j][0].u = *(const us8*)&bufc[rb + kq0];
            bf1[j][1].u = *(const us8*)&bufc[rb + kq1];
        }
        __builtin_amdgcn_s_barrier();
        __builtin_amdgcn_s_setprio(1);
#pragma unroll
        for (int ii = 0; ii < 4; ++ii)
#pragma unroll
            for (int j = 0; j < 2; ++j) {
                acc[ii + 4][j + 2] = mf16(af1[ii][0], bf1[j][0], acc[ii + 4][j + 2]);
                acc[ii + 4][j + 2] = mf16(af1[ii][1], bf1[j][1], acc[ii + 4][j + 2]);
            }
        __builtin_amdgcn_s_setprio(0);
        __builtin_amdgcn_s_barrier();

        // ========== P4: MFMA (af0 x bf1); boundary ========================
        __builtin_amdgcn_s_setprio(1);
#pragma unroll
        for (int ii = 0; ii < 4; ++ii)
#pragma unroll
            for (int j = 0; j < 2; ++j) {
                acc[ii][j + 2] = mf16(af0[ii][0], bf1[j][0], acc[ii][j + 2]);
                acc[ii][j + 2] = mf16(af0[ii][1], bf1[j][1], acc[ii][j + 2]);
            }
        __builtin_amdgcn_s_setprio(0);
        if (pf) {
            asm volatile("s_waitcnt vmcnt(0)" ::: "memory");  // k+1 landed
            __builtin_amdgcn_s_barrier();
        }
    }

    // ---- epilogue ----------------------------------------------------------
    if constexpr (MODE == 0) {
        if (n0 < E_) {
#pragma unroll
            for (int j = 0; j < 4; ++j) {
                const int col = n0 + wc * 64 + j * 16 + ln;
                const float bv = bias[col];
                const int h = (col & (E_ - 1)) >> 6, d = col & 63;
#pragma unroll
                for (int i = 0; i < 8; ++i) {
#pragma unroll
                    for (int r = 0; r < 4; ++r) {
                        const int row = m0 + wr * 128 + i * 16 + quad * 4 + r;
                        const int b = row >> 11, s = row & (S_ - 1);
                        O0[((size_t)(b * 16 + h) * S_ + s) * 64 + d] =
                            bhi((acc[i][j][r] + bv) * QSCL);
                    }
                }
            }
        } else if (n0 < 2 * E_) {
#pragma unroll
            for (int j = 0; j < 4; ++j) {
                const int col = n0 + wc * 64 + j * 16 + ln;
                const float bv = bias[col];
                const int h = (col & (E_ - 1)) >> 6, d = col & 63;
#pragma unroll
                for (int i = 0; i < 8; ++i) {
#pragma unroll
                    for (int r = 0; r < 4; ++r) {
                        const int row = m0 + wr * 128 + i * 16 + quad * 4 + r;
                        const int b = row >> 11, s = row & (S_ - 1);
                        O1[((size_t)(b * 16 + h) * S_ + s) * 64 +
                           (((d >> 3) ^ (s & 7)) * 8) + (d & 7)] =
                            bhi(acc[i][j][r] + bv);
                    }
                }
            }
        } else {
#pragma unroll
            for (int j = 0; j < 4; ++j) {
                const int col = n0 + wc * 64 + j * 16 + ln;
                const float bv = bias[col];
                const int h = (col & (E_ - 1)) >> 6, d = col & 63;
#pragma unroll
                for (int i = 0; i < 8; ++i) {
                    const int row0 = m0 + wr * 128 + i * 16 + quad * 4;
                    const int b = row0 >> 11, s0 = row0 & (S_ - 1);
                    const int tile = s0 >> 6;
                    const int g = (s0 >> 3) & 7;
                    us4 o;
#pragma unroll
                    for (int r = 0; r < 4; ++r) o[r] = bhi(acc[i][j][r] + bv);
                    *(us4*)&O2[(size_t)(b * 16 + h) * S_ * 64 + tile * 4096 +
                               d * 64 + ((g ^ (d & 7)) * 8) + (quad & 1) * 4] = o;
                }
            }
        }
    } else {
#pragma unroll
        for (int j = 0; j < 4; ++j) {
            const int col = n0 + wc * 64 + j * 16 + ln;
            const float bv = bias[col];
#pragma unroll
            for (int i = 0; i < 8; ++i) {
                const int row = m0 + wr * 128 + i * 16 + quad * 4;
#pragma unroll
                for (int r = 0; r < 4; ++r)
                    Cf[(size_t)(row + r) * E_ + col] = acc[i][j][r] + bv;
            }
        }
    }
}

// ---------------------------------------------------------------------------
// Flash attention v5 (unchanged): Q-tile 128, plain bf16, fp32 accum,
// exp2-folded softmax. Epilogue writes ctx2 PLAIN [M][2E]={hi|lo}.
// ---------------------------------------------------------------------------
__global__ __launch_bounds__(256, 4) void attn_mfma5(
    const unsigned short* __restrict__ Qb, const unsigned short* __restrict__ K2,
    const unsigned short* __restrict__ Vt2, const float* __restrict__ rel_bias,
    unsigned short* __restrict__ ctx2)
{
    __shared__ unsigned short Kt[64 * 64];    // 8 KB
    __shared__ unsigned short Vt[64 * 64];    // 8 KB
    __shared__ unsigned short Pt[128 * 72];   // 18 KB
    __shared__ float bias_s[65];

    const int t    = threadIdx.x;
    const int w    = t >> 6;
    const int lane = t & 63;
    const int ln   = lane & 15;
    const int quad = lane >> 4;

    const int bh = blockIdx.x;
    const int b  = bh >> 4;
    const int h  = bh & 15;
    const int q0 = blockIdx.y * 128;

    if (t < 65) {
        float s = 0.f;
#pragma unroll
        for (int hh = 0; hh < 16; ++hh) s += rel_bias[t * 16 + hh];
        bias_s[t] = s * (L2E / 16.f);
    }

    frag_cvt qf[2][2];
#pragma unroll
    for (int mf = 0; mf < 2; ++mf) {
        const unsigned short* qp =
            Qb + ((size_t)bh * S_ + q0 + w * 32 + mf * 16 + ln) * 64;
        qf[mf][0].u = *(const us8*)(qp + quad * 8);
        qf[mf][1].u = *(const us8*)(qp + 32 + quad * 8);
    }

    frag_cvt ones;
#pragma unroll
    for (int j = 0; j < 8; ++j) ones.u[j] = 0x3F80;

    f32x4 O[2][4];
#pragma unroll
    for (int mf = 0; mf < 2; ++mf)
#pragma unroll
        for (int n = 0; n < 4; ++n) O[mf][n] = (f32x4){0.f, 0.f, 0.f, 0.f};
    f32x4 lacc[2] = {(f32x4){0.f, 0.f, 0.f, 0.f}, (f32x4){0.f, 0.f, 0.f, 0.f}};

    const unsigned short* Kg = K2  + (size_t)bh * S_ * 64;
    const unsigned short* Vg = Vt2 + (size_t)bh * S_ * 64;

    for (int k0 = 0; k0 < S_; k0 += 64) {
        __syncthreads();
        {
            const unsigned short* kg = Kg + (size_t)k0 * 64;
            const unsigned short* vg = Vg + (size_t)k0 * 64;
            const int uo = w * 512;
            async_copy16(kg + uo + lane * 8,        &Kt[uo]);
            async_copy16(kg + 2048 + uo + lane * 8, &Kt[2048 + uo]);
            async_copy16(vg + uo + lane * 8,        &Vt[uo]);
            async_copy16(vg + 2048 + uo + lane * 8, &Vt[2048 + uo]);
        }
        __syncthreads();

        f32x4 sa[2][4];
#pragma unroll
        for (int n = 0; n < 4; ++n) {
            sa[0][n] = (f32x4){0.f, 0.f, 0.f, 0.f};
            sa[1][n] = (f32x4){0.f, 0.f, 0.f, 0.f};
            const int ro = (n * 16 + ln) * 64;
#pragma unroll
            for (int ks = 0; ks < 2; ++ks) {
                frag_cvt kh;
                kh.u = *(const us8*)&Kt[ro + (((ks * 4 + quad) ^ (ln & 7)) * 8)];
                sa[0][n] = __builtin_amdgcn_mfma_f32_16x16x32_bf16(
                    qf[0][ks].b, kh.b, sa[0][n], 0, 0, 0);
                sa[1][n] = __builtin_amdgcn_mfma_f32_16x16x32_bf16(
                    qf[1][ks].b, kh.b, sa[1][n], 0, 0, 0);
            }
        }

        const bool inband = (k0 >= q0 - 64) && (k0 <= q0 + 128);
        float cb = 0.f;
        if (!inband) cb = bias_s[(k0 < q0) ? 64 : 0];
#pragma unroll
        for (int mf = 0; mf < 2; ++mf) {
#pragma unroll
            for (int n = 0; n < 4; ++n) {
#pragma unroll
                for (int r = 0; r < 4; ++r) {
                    float s2;
                    if (inband) {
                        const int q   = q0 + w * 32 + mf * 16 + quad * 4 + r;
                        const int key = k0 + n * 16 + ln;
                        int rel = q - key;
                        rel = (rel < -MRD) ? -MRD : (rel > MRD ? MRD : rel);
                        s2 = sa[mf][n][r] + bias_s[rel + MRD];
                    } else {
                        s2 = sa[mf][n][r] + cb;
                    }
                    const int qrow = w * 32 + mf * 16 + quad * 4 + r;
                    const int pos = (n * 16 + ln) ^ ((qrow & 8) << 1);
                    Pt[qrow * 72 + pos] = bhi(__builtin_amdgcn_exp2f(s2));
                }
            }
        }

#pragma unroll
        for (int ks = 0; ks < 2; ++ks) {
            frag_cvt pa[2];
#pragma unroll
            for (int mf = 0; mf < 2; ++mf) {
                const int prow = w * 32 + mf * 16 + ln;
                pa[mf].u = *(const us8*)&Pt[prow * 72 +
                           ((ks * 32 + quad * 8) ^ ((prow & 8) << 1))];
                lacc[mf] = __builtin_amdgcn_mfma_f32_16x16x32_bf16(
                    pa[mf].b, ones.b, lacc[mf], 0, 0, 0);
            }
#pragma unroll
            for (int n = 0; n < 4; ++n) {
                frag_cvt vh;
                vh.u = *(const us8*)&Vt[(n * 16 + ln) * 64 +
                                        (((ks * 4 + quad) ^ (ln & 7)) * 8)];
                O[0][n] = __builtin_amdgcn_mfma_f32_16x16x32_bf16(
                    pa[0].b, vh.b, O[0][n], 0, 0, 0);
                O[1][n] = __builtin_amdgcn_mfma_f32_16x16x32_bf16(
                    pa[1].b, vh.b, O[1][n], 0, 0, 0);
            }
        }
    }

#pragma unroll
    for (int mf = 0; mf < 2; ++mf) {
        float inv[4];
#pragma unroll
        for (int r = 0; r < 4; ++r) inv[r] = 1.f / lacc[mf][r];
#pragma unroll
        for (int n = 0; n < 4; ++n) {
            const int k = h * D_ + n * 16 + ln;
#pragma unroll
            for (int r = 0; r < 4; ++r) {
                const int q = q0 + w * 32 + mf * 16 + quad * 4 + r;
                const float v = O[mf][n][r] * inv[r];
                unsigned short hb = bhi(v);
                const size_t rb = (size_t)(b * S_ + q) * (2 * E_);
                ctx2[rb + k]      = hb;
                ctx2[rb + E_ + k] = bhi(v - bf16_f(hb));
            }
        }
    }
}

// ---------------------------------------------------------------------------
extern "C" void kernel_launch(void* const* d_in, const int* in_sizes, int n_in,
                              void* d_out, int out_size, void* d_ws, size_t ws_size,
                              hipStream_t stream)
{
    const float* x         = (const float*)d_in[0];
    const float* in_proj_w = (const float*)d_in[1];
    const float* in_proj_b = (const float*)d_in[2];
    const float* out_w     = (const float*)d_in[3];
    const float* out_b     = (const float*)d_in[4];
    const float* rel_bias  = (const float*)d_in[5];
    float* out = (float*)d_out;

    const int M = B_ * S_;                         // 8192
    const size_t PH = (size_t)B_ * H_ * S_ * 64;   // 8.39M ushorts

    unsigned short* Qb   = (unsigned short*)d_ws;
    unsigned short* K2   = Qb + PH;
    unsigned short* Vt2  = K2 + PH;
    unsigned short* W2o  = Vt2 + PH;
    unsigned short* Wqkv = W2o + (size_t)E_ * 2 * E_;
    unsigned short* A2c  = Wqkv + (size_t)3 * E_ * E_;
    unsigned short* Axb  = A2c;   // overlap: Axb dead before attn writes A2c

    // 1) convert x and in_proj_w to plain bf16
    cvt_bf16<<<M,      128, 0, stream>>>(x,         Axb,  E_);
    cvt_bf16<<<3 * E_, 128, 0, stream>>>(in_proj_w, Wqkv, E_);

    // 2) QKV projection (m201-geometry core) -> Qb / K2 / Vt2
    {
        dim3 grid(M / 256, (3 * E_) / 256);   // 32 x 12 = 384 blocks
        gemm256<0><<<grid, 512, 0, stream>>>(Axb, Wqkv, in_proj_b,
                                             Qb, K2, Vt2, nullptr);
    }
    // 3) attention -> A2c (plain [hi|lo])
    {
        dim3 grid(B_ * H_, S_ / 128);
        attn_mfma5<<<grid, 256, 0, stream>>>(Qb, K2, Vt2, rel_bias, A2c);
    }
    // 4) split out_w, 3-term output projection (virtual K=3072)
    split_hilo<<<E_, 128, 0, stream>>>(out_w, W2o, E_);
    {
        dim3 grid(M / 256, E_ / 256);         // 32 x 4 = 128 blocks
        gemm256<1><<<grid, 512, 0, stream>>>(A2c, W2o, out_b,
                                             nullptr, nullptr, nullptr, out);
    }
}

// Round 6
// 327.272 us; speedup vs baseline: 1.0755x; 1.0755x over previous
//
#include <hip/hip_runtime.h>
#include <math.h>

#define B_ 4
#define S_ 2048
#define E_ 1024
#define H_ 16
#define D_ 64
#define MRD 32

typedef __bf16 bf16x8 __attribute__((ext_vector_type(8)));
typedef float f32x4 __attribute__((ext_vector_type(4)));
typedef float f32x16 __attribute__((ext_vector_type(16)));
typedef unsigned short us8 __attribute__((ext_vector_type(8)));
typedef unsigned short us4 __attribute__((ext_vector_type(4)));

union frag_cvt { us8 u; bf16x8 b; };
union h_cvt { __bf16 h; unsigned short u; };
union f_u { float f; unsigned int u; };

__device__ __forceinline__ unsigned short bhi(float x) {
    h_cvt c; c.h = (__bf16)x; return c.u;
}
__device__ __forceinline__ float bf16_f(unsigned short h) {
    union { unsigned int u; float f; } c;
    c.u = ((unsigned int)h) << 16;
    return c.f;
}

__device__ __forceinline__ void async_copy16(const void* g, void* l) {
    __builtin_amdgcn_global_load_lds(
        (const __attribute__((address_space(1))) void*)g,
        (__attribute__((address_space(3))) void*)l,
        16, 0, 0);
}

__device__ __forceinline__ f32x16 mf32(const frag_cvt& a, const frag_cvt& b, f32x16 c) {
    return __builtin_amdgcn_mfma_f32_32x32x16_bf16(a.b, b.b, c, 0, 0, 0);
}

#define QSCL 0.18033688f    // 0.125 * log2(e) — folded into Qb at projection
#define L2E  1.44269504f

// ---------------------------------------------------------------------------
// Convert pass (ROUND-0): fp32 -> bf16, GROUP-SWIZZLED for gemm_qkv5 staging.
// ---------------------------------------------------------------------------
__global__ __launch_bounds__(128) void cvt_bf16(
    const float* __restrict__ in, unsigned short* __restrict__ out, int K)
{
    const int r  = blockIdx.x;
    const int k8 = threadIdx.x * 8;
    if (k8 >= K) return;
    const float* p = in + (size_t)r * K + k8;
    float4 a = *(const float4*)p;
    float4 b = *(const float4*)(p + 4);
    float xs[8] = {a.x, a.y, a.z, a.w, b.x, b.y, b.z, b.w};
    us8 hu;
#pragma unroll
    for (int j = 0; j < 8; ++j) hu[j] = bhi(xs[j]);
    const int pos = (k8 & ~31) + ((((k8 >> 3) & 3) ^ (r & 3)) * 8);
    *(us8*)&out[(size_t)r * K + pos] = hu;
}

// ---------------------------------------------------------------------------
// Split pass (ROUND-0): fp32 -> {hi|lo} bf16, group-swizzled (out_w only).
// ---------------------------------------------------------------------------
__global__ __launch_bounds__(128) void split_hilo(
    const float* __restrict__ in, unsigned short* __restrict__ out, int K)
{
    const int r  = blockIdx.x;
    const int k8 = threadIdx.x * 8;
    if (k8 >= K) return;
    const float* p = in + (size_t)r * K + k8;
    float4 a = *(const float4*)p;
    float4 b = *(const float4*)(p + 4);
    float xs[8] = {a.x, a.y, a.z, a.w, b.x, b.y, b.z, b.w};
    us8 hu, lu;
#pragma unroll
    for (int j = 0; j < 8; ++j) {
        unsigned short hb = bhi(xs[j]);
        hu[j] = hb;
        lu[j] = bhi(xs[j] - bf16_f(hb));
    }
    const int pos = (k8 & ~31) + ((((k8 >> 3) & 3) ^ (r & 3)) * 8);
    *(us8*)&out[(size_t)r * 2 * K + pos]     = hu;
    *(us8*)&out[(size_t)r * 2 * K + K + pos] = lu;
}

// ---------------------------------------------------------------------------
// QKV GEMM (ROUND-0, proven best): plain bf16, region epilogue ->
//   Qb (pre-scaled), K2 (granule-swizzled), Vt2 (transposed+swizzled).
// ---------------------------------------------------------------------------
__global__ __launch_bounds__(256, 2) void gemm_qkv5(
    const unsigned short* __restrict__ Ab, const unsigned short* __restrict__ Bb,
    const float* __restrict__ bias, unsigned short* __restrict__ Qb,
    unsigned short* __restrict__ K2, unsigned short* __restrict__ Vt2,
    int M, int N, int K)
{
    __shared__ unsigned short At[128 * 32];
    __shared__ unsigned short Bt[128 * 32];

    const int t    = threadIdx.x;
    const int w    = t >> 6;
    const int lane = t & 63;
    const int ln   = lane & 15;
    const int quad = lane >> 4;
    const int wm   = w >> 1;
    const int wn   = w & 1;
    const int m0   = blockIdx.x * 128;
    const int n0   = blockIdx.y * 128;

    const int srow = w * 16 + (lane >> 2);
    const int scol = (lane & 3) * 8;
    const unsigned short* Abase = Ab + (size_t)(m0 + srow) * K + scol;
    const unsigned short* Bbase = Bb + (size_t)(n0 + srow) * K + scol;
    const int wlds = (w * 16) * 32;
    const int fro  = (quad ^ (ln & 3)) * 8;

    f32x4 acc[4][4];
#pragma unroll
    for (int i = 0; i < 4; ++i)
#pragma unroll
        for (int j = 0; j < 4; ++j)
            acc[i][j] = (f32x4){0.f, 0.f, 0.f, 0.f};

    for (int kk = 0; kk < K; kk += 32) {
        __syncthreads();
#pragma unroll
        for (int c = 0; c < 2; ++c) {
            const size_t ro = (size_t)(c * 64) * K;
            const int lo = c * 64 * 32 + wlds;
            async_copy16(Abase + ro + kk, &At[lo]);
            async_copy16(Bbase + ro + kk, &Bt[lo]);
        }
        __syncthreads();

        frag_cvt ah[4], bh[4];
#pragma unroll
        for (int i = 0; i < 4; ++i) {
            ah[i].u = *(const us8*)&At[(wm * 64 + i * 16 + ln) * 32 + fro];
            bh[i].u = *(const us8*)&Bt[(wn * 64 + i * 16 + ln) * 32 + fro];
        }
#pragma unroll
        for (int i = 0; i < 4; ++i)
#pragma unroll
            for (int j = 0; j < 4; ++j)
                acc[i][j] = __builtin_amdgcn_mfma_f32_16x16x32_bf16(
                    ah[i].b, bh[j].b, acc[i][j], 0, 0, 0);
    }

    if (n0 < E_) {
#pragma unroll
        for (int j = 0; j < 4; ++j) {
            const int col = n0 + wn * 64 + j * 16 + ln;
            const float bv = bias[col];
            const int h = (col & (E_ - 1)) >> 6, d = col & 63;
#pragma unroll
            for (int i = 0; i < 4; ++i) {
#pragma unroll
                for (int r = 0; r < 4; ++r) {
                    const int row = m0 + wm * 64 + i * 16 + quad * 4 + r;
                    const int b = row >> 11, s = row & (S_ - 1);
                    Qb[((size_t)(b * 16 + h) * S_ + s) * 64 + d] =
                        bhi((acc[i][j][r] + bv) * QSCL);
                }
            }
        }
    } else if (n0 < 2 * E_) {
#pragma unroll
        for (int j = 0; j < 4; ++j) {
            const int col = n0 + wn * 64 + j * 16 + ln;
            const float bv = bias[col];
            const int h = (col & (E_ - 1)) >> 6, d = col & 63;
#pragma unroll
            for (int i = 0; i < 4; ++i) {
#pragma unroll
                for (int r = 0; r < 4; ++r) {
                    const int row = m0 + wm * 64 + i * 16 + quad * 4 + r;
                    const int b = row >> 11, s = row & (S_ - 1);
                    K2[((size_t)(b * 16 + h) * S_ + s) * 64 +
                       (((d >> 3) ^ (s & 7)) * 8) + (d & 7)] =
                        bhi(acc[i][j][r] + bv);
                }
            }
        }
    } else {
#pragma unroll
        for (int j = 0; j < 4; ++j) {
            const int col = n0 + wn * 64 + j * 16 + ln;
            const float bv = bias[col];
            const int h = (col & (E_ - 1)) >> 6, d = col & 63;
#pragma unroll
            for (int i = 0; i < 4; ++i) {
                const int row0 = m0 + wm * 64 + i * 16 + quad * 4;
                const int b = row0 >> 11, s0 = row0 & (S_ - 1);
                const int tile = s0 >> 6;
                const int g = (s0 >> 3) & 7;
                us4 o;
#pragma unroll
                for (int r = 0; r < 4; ++r) o[r] = bhi(acc[i][j][r] + bv);
                *(us4*)&Vt2[(size_t)(b * 16 + h) * S_ * 64 + tile * 4096 +
                            d * 64 + ((g ^ (d & 7)) * 8) + (quad & 1) * 4] = o;
            }
        }
    }
}

// ---------------------------------------------------------------------------
// Flash attention v6.1: 32x32x16 MFMA, SWAPPED QK^T, in-register softmax,
// P->A-frag via __builtin_amdgcn_permlane32_swap (builtin, not raw asm —
// hazard-safe), double-buffered K/V staging with __syncthreads boundary
// (vmcnt+lgkmcnt drain: architecturally race-free; stage issued a full tile
// earlier so the drain is cheap).
//
// Layout facts used (gfx950, verified m74/m101 + HK m214-v22 swap recipe):
//   C 32x32: col = lane&31, row = (reg&3) + 8*(reg>>2) + 4*(lane>>5)
//   A-frag:  row = lane&31, k = (lane>>5)*8 + e   (8 bf16/lane)
//   B-frag:  col = lane&31, k = (lane>>5)*8 + e
//   permlane32_swap(lowGran, highGran) -> frag words [r0[0],r1[0],r0[1],r1[1]]
// ---------------------------------------------------------------------------
__global__ __launch_bounds__(256, 3) void attn_mfma6(
    const unsigned short* __restrict__ Qb, const unsigned short* __restrict__ K2,
    const unsigned short* __restrict__ Vt2, const float* __restrict__ rel_bias,
    unsigned short* __restrict__ ctx2)
{
    __shared__ unsigned short Kt[2][4096];   // 2 x 8 KB  (64 keys x 64 d)
    __shared__ unsigned short Vt[2][4096];   // 2 x 8 KB  (V^T: 64 d x 64 keys)
    __shared__ float bias_s[65];
    __shared__ float rsum[4][32];

    const int t    = threadIdx.x;
    const int w    = t >> 6;
    const int lane = t & 63;
    const int l31  = lane & 31;
    const int h    = lane >> 5;
    const int swzk = lane & 7;               // (row&7) for this lane's rows

    const int bh = blockIdx.x;
    const int b  = bh >> 4;
    const int hh = bh & 15;
    const int q0 = blockIdx.y * 128;

    if (t < 65) {
        float s = 0.f;
#pragma unroll
        for (int j = 0; j < 16; ++j) s += rel_bias[t * 16 + j];
        bias_s[t] = s * (L2E / 16.f);
    }

    // Q as B-frag: col q = l31 (rows q0+w*32+l31), k = h*8+e per 16-d chunk.
    frag_cvt qf[4];
    {
        const unsigned short* qp =
            Qb + ((size_t)bh * S_ + q0 + w * 32 + l31) * 64 + h * 8;
#pragma unroll
        for (int ks = 0; ks < 4; ++ks) qf[ks].u = *(const us8*)(qp + ks * 16);
    }

    f32x16 Z;
#pragma unroll
    for (int i = 0; i < 16; ++i) Z[i] = 0.f;
    f32x16 O0 = Z, O1 = Z;
    float lsum = 0.f;

    const unsigned short* Kg = K2  + (size_t)bh * S_ * 64;
    const unsigned short* Vg = Vt2 + (size_t)bh * S_ * 64;

    // ---- prologue: stage tile 0 into buffer 0 -----------------------------
    {
        const int uo = w * 512;
        async_copy16(Kg + uo + lane * 8,        &Kt[0][uo]);
        async_copy16(Kg + 2048 + uo + lane * 8, &Kt[0][2048 + uo]);
        async_copy16(Vg + uo + lane * 8,        &Vt[0][uo]);
        async_copy16(Vg + 2048 + uo + lane * 8, &Vt[0][2048 + uo]);
    }
    __syncthreads();

    for (int kt0 = 0; kt0 < 32; ++kt0) {
        const int cur = kt0 & 1;
        const int k0  = kt0 * 64;

        // issue next-tile stage early (T14): hides under this tile's compute
        if (kt0 + 1 < 32) {
            const unsigned short* kg = Kg + (size_t)(k0 + 64) * 64;
            const unsigned short* vg = Vg + (size_t)(k0 + 64) * 64;
            unsigned short* kd = Kt[cur ^ 1];
            unsigned short* vd = Vt[cur ^ 1];
            const int uo = w * 512;
            async_copy16(kg + uo + lane * 8,        kd + uo);
            async_copy16(kg + 2048 + uo + lane * 8, kd + 2048 + uo);
            async_copy16(vg + uo + lane * 8,        vd + uo);
            async_copy16(vg + 2048 + uo + lane * 8, vd + 2048 + uo);
        }

        // ---- QK^T swapped: sa = K-tile-half · Q^T -------------------------
        f32x16 sa0 = Z, sa1 = Z;
#pragma unroll
        for (int ks = 0; ks < 4; ++ks) {
            frag_cvt kh0, kh1;
            const int go = ((ks * 2 + h) ^ swzk) * 8;   // d-granule position
            kh0.u = *(const us8*)&Kt[cur][l31 * 64 + go];
            kh1.u = *(const us8*)&Kt[cur][(32 + l31) * 64 + go];
            sa0 = mf32(kh0, qf[ks], sa0);
            sa1 = mf32(kh1, qf[ks], sa1);
        }

        // ---- softmax in registers -----------------------------------------
        const bool inband = (k0 >= q0 - 64) && (k0 <= q0 + 128);
        float cb = 0.f;
        if (!inband) cb = bias_s[(k0 < q0) ? 64 : 0];
        const int q = q0 + w * 32 + l31;

        unsigned int Wd[2][4][2];
#pragma unroll
        for (int kt = 0; kt < 2; ++kt) {
#pragma unroll
            for (int B2 = 0; B2 < 4; ++B2) {
#pragma unroll
                for (int p = 0; p < 2; ++p) {
                    unsigned int word = 0;
#pragma unroll
                    for (int rp = 0; rp < 2; ++rp) {
                        const int reg = B2 * 4 + p * 2 + rp;
                        const float sv = (kt == 0) ? sa0[reg] : sa1[reg];
                        float s2;
                        if (inband) {
                            const int key = k0 + kt * 32 + B2 * 8 + h * 4 + p * 2 + rp;
                            int rel = q - key;
                            rel = (rel < -MRD) ? -MRD : (rel > MRD ? MRD : rel);
                            s2 = sv + bias_s[rel + MRD];
                        } else {
                            s2 = sv + cb;
                        }
                        const float e = __builtin_amdgcn_exp2f(s2);
                        const unsigned short u = bhi(e);
                        lsum += bf16_f(u);          // sum of bf16-rounded P
                        word |= ((unsigned int)u) << (16 * rp);
                    }
                    Wd[kt][B2][p] = word;
                }
            }
        }

        // ---- PV: 4 steps of 16 keys, A-frag via builtin permlane32_swap ---
#pragma unroll
        for (int m = 0; m < 4; ++m) {
            const int kt  = m >> 1;
            const int sel = (m & 1) * 2;
            auto r0 = __builtin_amdgcn_permlane32_swap(
                Wd[kt][sel][0], Wd[kt][sel + 1][0], false, false);
            auto r1 = __builtin_amdgcn_permlane32_swap(
                Wd[kt][sel][1], Wd[kt][sel + 1][1], false, false);
            frag_cvt pa;
            union { us8 v; unsigned int d[4]; } uu;
            uu.d[0] = (unsigned int)r0[0];
            uu.d[1] = (unsigned int)r1[0];
            uu.d[2] = (unsigned int)r0[1];
            uu.d[3] = (unsigned int)r1[1];
            pa.u = uu.v;

            const int gv = ((m * 2 + h) ^ swzk) * 8;    // key-granule position
            frag_cvt v0, v1;
            v0.u = *(const us8*)&Vt[cur][l31 * 64 + gv];
            v1.u = *(const us8*)&Vt[cur][(32 + l31) * 64 + gv];
            O0 = mf32(pa, v0, O0);
            O1 = mf32(pa, v1, O1);
        }

        // ---- boundary: full drain (vmcnt+lgkmcnt) + barrier — race-free ---
        __syncthreads();
    }

    // ---- epilogue ---------------------------------------------------------
    // lsum holds this half's keys; partner half completes the row sum.
    {
        f_u lz; lz.f = lsum;
        auto rs = __builtin_amdgcn_permlane32_swap(lz.u, lz.u, false, false);
        f_u s0, s1; s0.u = (unsigned int)rs[0]; s1.u = (unsigned int)rs[1];
        const float inv = 1.f / (s0.f + s1.f);
        if (lane < 32) rsum[w][l31] = inv;
    }
    __syncthreads();

    float invq[16];
#pragma unroll
    for (int reg = 0; reg < 16; ++reg)
        invq[reg] = rsum[w][(reg & 3) + 8 * (reg >> 2) + 4 * h];

#pragma unroll
    for (int dblk = 0; dblk < 2; ++dblk) {
#pragma unroll
        for (int reg = 0; reg < 16; ++reg) {
            const int qrow = q0 + w * 32 + (reg & 3) + 8 * (reg >> 2) + 4 * h;
            const float v = ((dblk == 0) ? O0[reg] : O1[reg]) * invq[reg];
            const unsigned short hb = bhi(v);
            const int k = hh * 64 + dblk * 32 + l31;
            // A2c group-swizzle: pos = (k&~31) + ((kg ^ (q&3))*8) + (k&7)
            const int pos = (k & ~31) + (((l31 >> 3) ^ (reg & 3)) * 8) + (k & 7);
            const size_t rb = (size_t)(b * S_ + qrow) * (2 * E_);
            ctx2[rb + pos]      = hb;
            ctx2[rb + E_ + pos] = bhi(v - bf16_f(hb));
        }
    }
}

// ---------------------------------------------------------------------------
// Output projection (ROUND-0): split-bf16 NT GEMM (final fp32 output).
// ---------------------------------------------------------------------------
__global__ __launch_bounds__(256, 2) void gemm_out4(
    const unsigned short* __restrict__ A2, const unsigned short* __restrict__ B2,
    const float* __restrict__ bias, float* __restrict__ C,
    int M, int N, int K)
{
    __shared__ unsigned short Ath[128 * 32], Atl[128 * 32];
    __shared__ unsigned short Bth[128 * 32], Btl[128 * 32];

    const int t    = threadIdx.x;
    const int w    = t >> 6;
    const int lane = t & 63;
    const int ln   = lane & 15;
    const int quad = lane >> 4;
    const int wm   = w >> 1;
    const int wn   = w & 1;
    const int m0   = blockIdx.x * 128;
    const int n0   = blockIdx.y * 128;
    const int K2s  = 2 * K;

    const int srow = w * 16 + (lane >> 2);
    const int scol = (lane & 3) * 8;
    const unsigned short* Abase = A2 + (size_t)(m0 + srow) * K2s + scol;
    const unsigned short* Bbase = B2 + (size_t)(n0 + srow) * K2s + scol;
    const int wlds = (w * 16) * 32;
    const int fro  = (quad ^ (ln & 3)) * 8;

    f32x4 acc[4][4];
#pragma unroll
    for (int i = 0; i < 4; ++i)
#pragma unroll
        for (int j = 0; j < 4; ++j)
            acc[i][j] = (f32x4){0.f, 0.f, 0.f, 0.f};

    for (int kk = 0; kk < K; kk += 32) {
        __syncthreads();
#pragma unroll
        for (int c = 0; c < 2; ++c) {
            const size_t ro = (size_t)(c * 64) * K2s;
            const int lo = c * 64 * 32 + wlds;
            async_copy16(Abase + ro + kk,     &Ath[lo]);
            async_copy16(Abase + ro + K + kk, &Atl[lo]);
            async_copy16(Bbase + ro + kk,     &Bth[lo]);
            async_copy16(Bbase + ro + K + kk, &Btl[lo]);
        }
        __syncthreads();

        frag_cvt ah[4], al[4], bh[4], bl[4];
#pragma unroll
        for (int i = 0; i < 4; ++i) {
            const int ar = (wm * 64 + i * 16 + ln) * 32 + fro;
            const int br = (wn * 64 + i * 16 + ln) * 32 + fro;
            ah[i].u = *(const us8*)&Ath[ar];
            al[i].u = *(const us8*)&Atl[ar];
            bh[i].u = *(const us8*)&Bth[br];
            bl[i].u = *(const us8*)&Btl[br];
        }
#pragma unroll
        for (int i = 0; i < 4; ++i)
#pragma unroll
            for (int j = 0; j < 4; ++j) {
                acc[i][j] = __builtin_amdgcn_mfma_f32_16x16x32_bf16(
                    ah[i].b, bh[j].b, acc[i][j], 0, 0, 0);
                acc[i][j] = __builtin_amdgcn_mfma_f32_16x16x32_bf16(
                    ah[i].b, bl[j].b, acc[i][j], 0, 0, 0);
                acc[i][j] = __builtin_amdgcn_mfma_f32_16x16x32_bf16(
                    al[i].b, bh[j].b, acc[i][j], 0, 0, 0);
            }
    }

#pragma unroll
    for (int j = 0; j < 4; ++j) {
        const int col = n0 + wn * 64 + j * 16 + ln;
        const float bv = bias[col];
#pragma unroll
        for (int i = 0; i < 4; ++i) {
            const int row = m0 + wm * 64 + i * 16 + quad * 4;
#pragma unroll
            for (int r = 0; r < 4; ++r)
                C[(size_t)(row + r) * N + col] = acc[i][j][r] + bv;
        }
    }
}

// ---------------------------------------------------------------------------
extern "C" void kernel_launch(void* const* d_in, const int* in_sizes, int n_in,
                              void* d_out, int out_size, void* d_ws, size_t ws_size,
                              hipStream_t stream)
{
    const float* x         = (const float*)d_in[0];
    const float* in_proj_w = (const float*)d_in[1];
    const float* in_proj_b = (const float*)d_in[2];
    const float* out_w     = (const float*)d_in[3];
    const float* out_b     = (const float*)d_in[4];
    const float* rel_bias  = (const float*)d_in[5];
    float* out = (float*)d_out;

    const int M = B_ * S_;                         // 8192
    const size_t PH = (size_t)B_ * H_ * S_ * 64;   // 8.39M ushorts

    // workspace (~112 MB) — ROUND-0 layout
    unsigned short* Qb   = (unsigned short*)d_ws;          // 16.8 MB
    unsigned short* K2   = Qb + PH;                        // 16.8 MB
    unsigned short* Vt2  = K2 + PH;                        // 16.8 MB
    unsigned short* A2c  = Vt2 + PH;                       // [M][2E] 33.6 MB
    unsigned short* Axb  = A2c + (size_t)M * 2 * E_;       // [M][E]  16.8 MB
    unsigned short* Wqkv = Axb + (size_t)M * E_;           // [3E][E]  6.3 MB
    unsigned short* W2o  = Wqkv + (size_t)3 * E_ * E_;     // [E][2E]  4.2 MB

    // 1) convert x and in_proj_w to bf16 (group-swizzled for gemm staging)
    cvt_bf16<<<M,      128, 0, stream>>>(x,         Axb,  E_);
    cvt_bf16<<<3 * E_, 128, 0, stream>>>(in_proj_w, Wqkv, E_);

    // 2) QKV projection (round-0 kernel) -> Qb / K2 / Vt2
    {
        dim3 grid(M / 128, (3 * E_) / 128);
        gemm_qkv5<<<grid, 256, 0, stream>>>(Axb, Wqkv, in_proj_b, Qb, K2, Vt2,
                                            M, 3 * E_, E_);
    }
    // 3) attention v6.1 (32x32 swapped + in-register softmax) -> A2c
    {
        dim3 grid(B_ * H_, S_ / 128);
        attn_mfma6<<<grid, 256, 0, stream>>>(Qb, K2, Vt2, rel_bias, A2c);
    }
    // 4) split out_w, output projection (round-0 kernel)
    split_hilo<<<E_, 128, 0, stream>>>(out_w, W2o, E_);
    {
        dim3 grid(M / 128, E_ / 128);
        gemm_out4<<<grid, 256, 0, stream>>>(A2c, W2o, out_b, out, M, E_, E_);
    }
}

// Round 8
// 320.126 us; speedup vs baseline: 1.0995x; 1.0223x over previous
//
#include <hip/hip_runtime.h>
#include <math.h>

#define B_ 4
#define S_ 2048
#define E_ 1024
#define H_ 16
#define D_ 64
#define MRD 32

typedef __bf16 bf16x8 __attribute__((ext_vector_type(8)));
typedef float f32x4 __attribute__((ext_vector_type(4)));
typedef float f32x16 __attribute__((ext_vector_type(16)));
typedef unsigned short us8 __attribute__((ext_vector_type(8)));
typedef unsigned short us4 __attribute__((ext_vector_type(4)));

union frag_cvt { us8 u; bf16x8 b; };
union h_cvt { __bf16 h; unsigned short u; };

__device__ __forceinline__ unsigned short bhi(float x) {
    h_cvt c; c.h = (__bf16)x; return c.u;
}
__device__ __forceinline__ float bf16_f(unsigned short h) {
    union { unsigned int u; float f; } c;
    c.u = ((unsigned int)h) << 16;
    return c.f;
}

__device__ __forceinline__ void async_copy16(const void* g, void* l) {
    __builtin_amdgcn_global_load_lds(
        (const __attribute__((address_space(1))) void*)g,
        (__attribute__((address_space(3))) void*)l,
        16, 0, 0);
}

__device__ __forceinline__ f32x16 mf32(const frag_cvt& a, const frag_cvt& b, f32x16 c) {
    return __builtin_amdgcn_mfma_f32_32x32x16_bf16(a.b, b.b, c, 0, 0, 0);
}

#define QSCL 0.18033688f    // 0.125 * log2(e) — folded into Qb at projection
#define L2E  1.44269504f

// ---------------------------------------------------------------------------
// Convert pass (ROUND-0): fp32 -> bf16, GROUP-SWIZZLED for gemm_qkv5 staging.
// ---------------------------------------------------------------------------
__global__ __launch_bounds__(128) void cvt_bf16(
    const float* __restrict__ in, unsigned short* __restrict__ out, int K)
{
    const int r  = blockIdx.x;
    const int k8 = threadIdx.x * 8;
    if (k8 >= K) return;
    const float* p = in + (size_t)r * K + k8;
    float4 a = *(const float4*)p;
    float4 b = *(const float4*)(p + 4);
    float xs[8] = {a.x, a.y, a.z, a.w, b.x, b.y, b.z, b.w};
    us8 hu;
#pragma unroll
    for (int j = 0; j < 8; ++j) hu[j] = bhi(xs[j]);
    const int pos = (k8 & ~31) + ((((k8 >> 3) & 3) ^ (r & 3)) * 8);
    *(us8*)&out[(size_t)r * K + pos] = hu;
}

// ---------------------------------------------------------------------------
// Split pass (ROUND-0): fp32 -> {hi|lo} bf16, group-swizzled (out_w only).
// ---------------------------------------------------------------------------
__global__ __launch_bounds__(128) void split_hilo(
    const float* __restrict__ in, unsigned short* __restrict__ out, int K)
{
    const int r  = blockIdx.x;
    const int k8 = threadIdx.x * 8;
    if (k8 >= K) return;
    const float* p = in + (size_t)r * K + k8;
    float4 a = *(const float4*)p;
    float4 b = *(const float4*)(p + 4);
    float xs[8] = {a.x, a.y, a.z, a.w, b.x, b.y, b.z, b.w};
    us8 hu, lu;
#pragma unroll
    for (int j = 0; j < 8; ++j) {
        unsigned short hb = bhi(xs[j]);
        hu[j] = hb;
        lu[j] = bhi(xs[j] - bf16_f(hb));
    }
    const int pos = (k8 & ~31) + ((((k8 >> 3) & 3) ^ (r & 3)) * 8);
    *(us8*)&out[(size_t)r * 2 * K + pos]     = hu;
    *(us8*)&out[(size_t)r * 2 * K + K + pos] = lu;
}

// ---------------------------------------------------------------------------
// QKV GEMM (ROUND-0, proven best): plain bf16, region epilogue ->
//   Qb (pre-scaled), K2 (granule-swizzled), Vt2 (transposed+swizzled).
// ---------------------------------------------------------------------------
__global__ __launch_bounds__(256, 2) void gemm_qkv5(
    const unsigned short* __restrict__ Ab, const unsigned short* __restrict__ Bb,
    const float* __restrict__ bias, unsigned short* __restrict__ Qb,
    unsigned short* __restrict__ K2, unsigned short* __restrict__ Vt2,
    int M, int N, int K)
{
    __shared__ unsigned short At[128 * 32];
    __shared__ unsigned short Bt[128 * 32];

    const int t    = threadIdx.x;
    const int w    = t >> 6;
    const int lane = t & 63;
    const int ln   = lane & 15;
    const int quad = lane >> 4;
    const int wm   = w >> 1;
    const int wn   = w & 1;
    const int m0   = blockIdx.x * 128;
    const int n0   = blockIdx.y * 128;

    const int srow = w * 16 + (lane >> 2);
    const int scol = (lane & 3) * 8;
    const unsigned short* Abase = Ab + (size_t)(m0 + srow) * K + scol;
    const unsigned short* Bbase = Bb + (size_t)(n0 + srow) * K + scol;
    const int wlds = (w * 16) * 32;
    const int fro  = (quad ^ (ln & 3)) * 8;

    f32x4 acc[4][4];
#pragma unroll
    for (int i = 0; i < 4; ++i)
#pragma unroll
        for (int j = 0; j < 4; ++j)
            acc[i][j] = (f32x4){0.f, 0.f, 0.f, 0.f};

    for (int kk = 0; kk < K; kk += 32) {
        __syncthreads();
#pragma unroll
        for (int c = 0; c < 2; ++c) {
            const size_t ro = (size_t)(c * 64) * K;
            const int lo = c * 64 * 32 + wlds;
            async_copy16(Abase + ro + kk, &At[lo]);
            async_copy16(Bbase + ro + kk, &Bt[lo]);
        }
        __syncthreads();

        frag_cvt ah[4], bh[4];
#pragma unroll
        for (int i = 0; i < 4; ++i) {
            ah[i].u = *(const us8*)&At[(wm * 64 + i * 16 + ln) * 32 + fro];
            bh[i].u = *(const us8*)&Bt[(wn * 64 + i * 16 + ln) * 32 + fro];
        }
#pragma unroll
        for (int i = 0; i < 4; ++i)
#pragma unroll
            for (int j = 0; j < 4; ++j)
                acc[i][j] = __builtin_amdgcn_mfma_f32_16x16x32_bf16(
                    ah[i].b, bh[j].b, acc[i][j], 0, 0, 0);
    }

    if (n0 < E_) {
#pragma unroll
        for (int j = 0; j < 4; ++j) {
            const int col = n0 + wn * 64 + j * 16 + ln;
            const float bv = bias[col];
            const int h = (col & (E_ - 1)) >> 6, d = col & 63;
#pragma unroll
            for (int i = 0; i < 4; ++i) {
#pragma unroll
                for (int r = 0; r < 4; ++r) {
                    const int row = m0 + wm * 64 + i * 16 + quad * 4 + r;
                    const int b = row >> 11, s = row & (S_ - 1);
                    Qb[((size_t)(b * 16 + h) * S_ + s) * 64 + d] =
                        bhi((acc[i][j][r] + bv) * QSCL);
                }
            }
        }
    } else if (n0 < 2 * E_) {
#pragma unroll
        for (int j = 0; j < 4; ++j) {
            const int col = n0 + wn * 64 + j * 16 + ln;
            const float bv = bias[col];
            const int h = (col & (E_ - 1)) >> 6, d = col & 63;
#pragma unroll
            for (int i = 0; i < 4; ++i) {
#pragma unroll
                for (int r = 0; r < 4; ++r) {
                    const int row = m0 + wm * 64 + i * 16 + quad * 4 + r;
                    const int b = row >> 11, s = row & (S_ - 1);
                    K2[((size_t)(b * 16 + h) * S_ + s) * 64 +
                       (((d >> 3) ^ (s & 7)) * 8) + (d & 7)] =
                        bhi(acc[i][j][r] + bv);
                }
            }
        }
    } else {
#pragma unroll
        for (int j = 0; j < 4; ++j) {
            const int col = n0 + wn * 64 + j * 16 + ln;
            const float bv = bias[col];
            const int h = (col & (E_ - 1)) >> 6, d = col & 63;
#pragma unroll
            for (int i = 0; i < 4; ++i) {
                const int row0 = m0 + wm * 64 + i * 16 + quad * 4;
                const int b = row0 >> 11, s0 = row0 & (S_ - 1);
                const int tile = s0 >> 6;
                const int g = (s0 >> 3) & 7;
                us4 o;
#pragma unroll
                for (int r = 0; r < 4; ++r) o[r] = bhi(acc[i][j][r] + bv);
                *(us4*)&Vt2[(size_t)(b * 16 + h) * S_ * 64 + tile * 4096 +
                            d * 64 + ((g ^ (d & 7)) * 8) + (quad & 1) * 4] = o;
            }
        }
    }
}

// ---------------------------------------------------------------------------
// Flash attention v6.3: the PASSING v6.1 data-path (builtin permlane only,
// __syncthreads boundary, NO inline asm anywhere) plus the two mechanism-safe
// reductions from the v6.2 plan:
//   - row-sum via MFMA-with-ones into lacc (matrix pipe; construct verified
//     in round-0's attn_mfma5).  Replaces the lsum VALU chain.
//   - epilogue: lacc C-layout row mapping == O's -> invq[reg] = 1/lacc[reg];
//     rsum LDS, permlane row-sum, and the final barrier are deleted.
// ---------------------------------------------------------------------------
__global__ __launch_bounds__(256, 3) void attn_mfma6(
    const unsigned short* __restrict__ Qb, const unsigned short* __restrict__ K2,
    const unsigned short* __restrict__ Vt2, const float* __restrict__ rel_bias,
    unsigned short* __restrict__ ctx2)
{
    __shared__ unsigned short Kt[2][4096];   // 2 x 8 KB  (64 keys x 64 d)
    __shared__ unsigned short Vt[2][4096];   // 2 x 8 KB  (V^T: 64 d x 64 keys)
    __shared__ float bias_s[65];

    const int t    = threadIdx.x;
    const int w    = t >> 6;
    const int lane = t & 63;
    const int l31  = lane & 31;
    const int h    = lane >> 5;
    const int swzk = lane & 7;               // (row&7) for this lane's rows

    const int bh = blockIdx.x;
    const int b  = bh >> 4;
    const int hh = bh & 15;
    const int q0 = blockIdx.y * 128;

    if (t < 65) {
        float s = 0.f;
#pragma unroll
        for (int j = 0; j < 16; ++j) s += rel_bias[t * 16 + j];
        bias_s[t] = s * (L2E / 16.f);
    }

    // Q as B-frag: col q = l31 (rows q0+w*32+l31), k = h*8+e per 16-d chunk.
    frag_cvt qf[4];
    {
        const unsigned short* qp =
            Qb + ((size_t)bh * S_ + q0 + w * 32 + l31) * 64 + h * 8;
#pragma unroll
        for (int ks = 0; ks < 4; ++ks) qf[ks].u = *(const us8*)(qp + ks * 16);
    }

    frag_cvt ones;
#pragma unroll
    for (int j = 0; j < 8; ++j) ones.u[j] = 0x3F80;

    f32x16 Z;
#pragma unroll
    for (int i = 0; i < 16; ++i) Z[i] = 0.f;
    f32x16 O0 = Z, O1 = Z, lacc = Z;

    const unsigned short* Kg = K2  + (size_t)bh * S_ * 64;
    const unsigned short* Vg = Vt2 + (size_t)bh * S_ * 64;

    // ---- prologue: stage tile 0 into buffer 0 -----------------------------
    {
        const int uo = w * 512;
        async_copy16(Kg + uo + lane * 8,        &Kt[0][uo]);
        async_copy16(Kg + 2048 + uo + lane * 8, &Kt[0][2048 + uo]);
        async_copy16(Vg + uo + lane * 8,        &Vt[0][uo]);
        async_copy16(Vg + 2048 + uo + lane * 8, &Vt[0][2048 + uo]);
    }
    __syncthreads();

    for (int kt0 = 0; kt0 < 32; ++kt0) {
        const int cur = kt0 & 1;
        const int k0  = kt0 * 64;

        // issue next-tile stage early (T14): hides under this tile's compute
        if (kt0 + 1 < 32) {
            const unsigned short* kg = Kg + (size_t)(k0 + 64) * 64;
            const unsigned short* vg = Vg + (size_t)(k0 + 64) * 64;
            unsigned short* kd = Kt[cur ^ 1];
            unsigned short* vd = Vt[cur ^ 1];
            const int uo = w * 512;
            async_copy16(kg + uo + lane * 8,        kd + uo);
            async_copy16(kg + 2048 + uo + lane * 8, kd + 2048 + uo);
            async_copy16(vg + uo + lane * 8,        vd + uo);
            async_copy16(vg + 2048 + uo + lane * 8, vd + 2048 + uo);
        }

        // ---- QK^T swapped: sa = K-tile-half · Q^T -------------------------
        f32x16 sa0 = Z, sa1 = Z;
#pragma unroll
        for (int ks = 0; ks < 4; ++ks) {
            frag_cvt kh0, kh1;
            const int go = ((ks * 2 + h) ^ swzk) * 8;   // d-granule position
            kh0.u = *(const us8*)&Kt[cur][l31 * 64 + go];
            kh1.u = *(const us8*)&Kt[cur][(32 + l31) * 64 + go];
            sa0 = mf32(kh0, qf[ks], sa0);
            sa1 = mf32(kh1, qf[ks], sa1);
        }

        // ---- softmax in registers (no lsum chain; bhi + pack, no asm) -----
        const bool inband = (k0 >= q0 - 64) && (k0 <= q0 + 128);
        float cb = 0.f;
        if (!inband) cb = bias_s[(k0 < q0) ? 64 : 0];
        const int q = q0 + w * 32 + l31;

        unsigned int Wd[2][4][2];
#pragma unroll
        for (int kt = 0; kt < 2; ++kt) {
#pragma unroll
            for (int B2 = 0; B2 < 4; ++B2) {
#pragma unroll
                for (int p = 0; p < 2; ++p) {
                    unsigned int word = 0;
#pragma unroll
                    for (int rp = 0; rp < 2; ++rp) {
                        const int reg = B2 * 4 + p * 2 + rp;
                        const float sv = (kt == 0) ? sa0[reg] : sa1[reg];
                        float s2;
                        if (inband) {
                            const int key = k0 + kt * 32 + B2 * 8 + h * 4 + p * 2 + rp;
                            int rel = q - key;
                            rel = (rel < -MRD) ? -MRD : (rel > MRD ? MRD : rel);
                            s2 = sv + bias_s[rel + MRD];
                        } else {
                            s2 = sv + cb;
                        }
                        const float e = __builtin_amdgcn_exp2f(s2);
                        word |= ((unsigned int)bhi(e)) << (16 * rp);
                    }
                    Wd[kt][B2][p] = word;
                }
            }
        }

        // ---- PV + row-sum: A-frag via builtin permlane32_swap -------------
#pragma unroll
        for (int m = 0; m < 4; ++m) {
            const int kt  = m >> 1;
            const int sel = (m & 1) * 2;
            auto r0 = __builtin_amdgcn_permlane32_swap(
                Wd[kt][sel][0], Wd[kt][sel + 1][0], false, false);
            auto r1 = __builtin_amdgcn_permlane32_swap(
                Wd[kt][sel][1], Wd[kt][sel + 1][1], false, false);
            frag_cvt pa;
            union { us8 v; unsigned int d[4]; } uu;
            uu.d[0] = (unsigned int)r0[0];
            uu.d[1] = (unsigned int)r1[0];
            uu.d[2] = (unsigned int)r0[1];
            uu.d[3] = (unsigned int)r1[1];
            pa.u = uu.v;

            lacc = mf32(pa, ones, lacc);                // row-sum, matrix pipe

            const int gv = ((m * 2 + h) ^ swzk) * 8;    // key-granule position
            frag_cvt v0, v1;
            v0.u = *(const us8*)&Vt[cur][l31 * 64 + gv];
            v1.u = *(const us8*)&Vt[cur][(32 + l31) * 64 + gv];
            O0 = mf32(pa, v0, O0);
            O1 = mf32(pa, v1, O1);
        }

        // ---- boundary: full drain (vmcnt+lgkmcnt) + barrier — race-free ---
        __syncthreads();
    }

    // ---- epilogue: lacc C-layout row mapping == O's -> direct reciprocal --
    float invq[16];
#pragma unroll
    for (int reg = 0; reg < 16; ++reg)
        invq[reg] = 1.f / lacc[reg];

#pragma unroll
    for (int dblk = 0; dblk < 2; ++dblk) {
#pragma unroll
        for (int reg = 0; reg < 16; ++reg) {
            const int qrow = q0 + w * 32 + (reg & 3) + 8 * (reg >> 2) + 4 * h;
            const float v = ((dblk == 0) ? O0[reg] : O1[reg]) * invq[reg];
            const unsigned short hb = bhi(v);
            const int k = hh * 64 + dblk * 32 + l31;
            // A2c group-swizzle: pos = (k&~31) + ((kg ^ (q&3))*8) + (k&7)
            const int pos = (k & ~31) + (((l31 >> 3) ^ (reg & 3)) * 8) + (k & 7);
            const size_t rb = (size_t)(b * S_ + qrow) * (2 * E_);
            ctx2[rb + pos]      = hb;
            ctx2[rb + E_ + pos] = bhi(v - bf16_f(hb));
        }
    }
}

// ---------------------------------------------------------------------------
// Output projection (ROUND-0): split-bf16 NT GEMM (final fp32 output).
// ---------------------------------------------------------------------------
__global__ __launch_bounds__(256, 2) void gemm_out4(
    const unsigned short* __restrict__ A2, const unsigned short* __restrict__ B2,
    const float* __restrict__ bias, float* __restrict__ C,
    int M, int N, int K)
{
    __shared__ unsigned short Ath[128 * 32], Atl[128 * 32];
    __shared__ unsigned short Bth[128 * 32], Btl[128 * 32];

    const int t    = threadIdx.x;
    const int w    = t >> 6;
    const int lane = t & 63;
    const int ln   = lane & 15;
    const int quad = lane >> 4;
    const int wm   = w >> 1;
    const int wn   = w & 1;
    const int m0   = blockIdx.x * 128;
    const int n0   = blockIdx.y * 128;
    const int K2s  = 2 * K;

    const int srow = w * 16 + (lane >> 2);
    const int scol = (lane & 3) * 8;
    const unsigned short* Abase = A2 + (size_t)(m0 + srow) * K2s + scol;
    const unsigned short* Bbase = B2 + (size_t)(n0 + srow) * K2s + scol;
    const int wlds = (w * 16) * 32;
    const int fro  = (quad ^ (ln & 3)) * 8;

    f32x4 acc[4][4];
#pragma unroll
    for (int i = 0; i < 4; ++i)
#pragma unroll
        for (int j = 0; j < 4; ++j)
            acc[i][j] = (f32x4){0.f, 0.f, 0.f, 0.f};

    for (int kk = 0; kk < K; kk += 32) {
        __syncthreads();
#pragma unroll
        for (int c = 0; c < 2; ++c) {
            const size_t ro = (size_t)(c * 64) * K2s;
            const int lo = c * 64 * 32 + wlds;
            async_copy16(Abase + ro + kk,     &Ath[lo]);
            async_copy16(Abase + ro + K + kk, &Atl[lo]);
            async_copy16(Bbase + ro + kk,     &Bth[lo]);
            async_copy16(Bbase + ro + K + kk, &Btl[lo]);
        }
        __syncthreads();

        frag_cvt ah[4], al[4], bh[4], bl[4];
#pragma unroll
        for (int i = 0; i < 4; ++i) {
            const int ar = (wm * 64 + i * 16 + ln) * 32 + fro;
            const int br = (wn * 64 + i * 16 + ln) * 32 + fro;
            ah[i].u = *(const us8*)&Ath[ar];
            al[i].u = *(const us8*)&Atl[ar];
            bh[i].u = *(const us8*)&Bth[br];
            bl[i].u = *(const us8*)&Btl[br];
        }
#pragma unroll
        for (int i = 0; i < 4; ++i)
#pragma unroll
            for (int j = 0; j < 4; ++j) {
                acc[i][j] = __builtin_amdgcn_mfma_f32_16x16x32_bf16(
                    ah[i].b, bh[j].b, acc[i][j], 0, 0, 0);
                acc[i][j] = __builtin_amdgcn_mfma_f32_16x16x32_bf16(
                    ah[i].b, bl[j].b, acc[i][j], 0, 0, 0);
                acc[i][j] = __builtin_amdgcn_mfma_f32_16x16x32_bf16(
                    al[i].b, bh[j].b, acc[i][j], 0, 0, 0);
            }
    }

#pragma unroll
    for (int j = 0; j < 4; ++j) {
        const int col = n0 + wn * 64 + j * 16 + ln;
        const float bv = bias[col];
#pragma unroll
        for (int i = 0; i < 4; ++i) {
            const int row = m0 + wm * 64 + i * 16 + quad * 4;
#pragma unroll
            for (int r = 0; r < 4; ++r)
                C[(size_t)(row + r) * N + col] = acc[i][j][r] + bv;
        }
    }
}

// ---------------------------------------------------------------------------
extern "C" void kernel_launch(void* const* d_in, const int* in_sizes, int n_in,
                              void* d_out, int out_size, void* d_ws, size_t ws_size,
                              hipStream_t stream)
{
    const float* x         = (const float*)d_in[0];
    const float* in_proj_w = (const float*)d_in[1];
    const float* in_proj_b = (const float*)d_in[2];
    const float* out_w     = (const float*)d_in[3];
    const float* out_b     = (const float*)d_in[4];
    const float* rel_bias  = (const float*)d_in[5];
    float* out = (float*)d_out;

    const int M = B_ * S_;                         // 8192
    const size_t PH = (size_t)B_ * H_ * S_ * 64;   // 8.39M ushorts

    // workspace (~112 MB) — ROUND-0 layout
    unsigned short* Qb   = (unsigned short*)d_ws;          // 16.8 MB
    unsigned short* K2   = Qb + PH;                        // 16.8 MB
    unsigned short* Vt2  = K2 + PH;                        // 16.8 MB
    unsigned short* A2c  = Vt2 + PH;                       // [M][2E] 33.6 MB
    unsigned short* Axb  = A2c + (size_t)M * 2 * E_;       // [M][E]  16.8 MB
    unsigned short* Wqkv = Axb + (size_t)M * E_;           // [3E][E]  6.3 MB
    unsigned short* W2o  = Wqkv + (size_t)3 * E_ * E_;     // [E][2E]  4.2 MB

    // 1) convert x and in_proj_w to bf16 (group-swizzled for gemm staging)
    cvt_bf16<<<M,      128, 0, stream>>>(x,         Axb,  E_);
    cvt_bf16<<<3 * E_, 128, 0, stream>>>(in_proj_w, Wqkv, E_);

    // 2) QKV projection (round-0 kernel) -> Qb / K2 / Vt2
    {
        dim3 grid(M / 128, (3 * E_) / 128);
        gemm_qkv5<<<grid, 256, 0, stream>>>(Axb, Wqkv, in_proj_b, Qb, K2, Vt2,
                                            M, 3 * E_, E_);
    }
    // 3) attention v6.3 (in-register softmax, MFMA row-sum, no asm) -> A2c
    {
        dim3 grid(B_ * H_, S_ / 128);
        attn_mfma6<<<grid, 256, 0, stream>>>(Qb, K2, Vt2, rel_bias, A2c);
    }
    // 4) split out_w, output projection (round-0 kernel)
    split_hilo<<<E_, 128, 0, stream>>>(out_w, W2o, E_);
    {
        dim3 grid(M / 128, E_ / 128);
        gemm_out4<<<grid, 256, 0, stream>>>(A2c, W2o, out_b, out, M, E_, E_);
    }
}